// Round 6
// baseline (394.682 us; speedup 1.0000x reference)
//
#include <hip/hip_runtime.h>
#include <cmath>

// ---------------- CSR build kernels ----------------

__global__ void hist_kernel(const int* __restrict__ dst, int* __restrict__ deg, int E) {
    int e = blockIdx.x * blockDim.x + threadIdx.x;
    if (e < E) atomicAdd(&deg[dst[e]], 1);
}

// ---- hierarchical exclusive scan over (deg[i]+1) -> rowptr[0..n], pos copy ----
__global__ void scan_bsum_kernel(const int* __restrict__ deg, int* __restrict__ bsum, int n) {
    __shared__ int s[256];
    int t = threadIdx.x;
    int base = blockIdx.x * 1024;
    int sum = 0;
#pragma unroll
    for (int j = 0; j < 4; j++) {
        int i = base + j * 256 + t;
        if (i < n) sum += deg[i] + 1;   // +1 self-loop
    }
    s[t] = sum;
    __syncthreads();
    for (int off = 128; off; off >>= 1) {
        if (t < off) s[t] += s[t + off];
        __syncthreads();
    }
    if (t == 0) bsum[blockIdx.x] = s[0];
}

__global__ void scan_bsum_scan_kernel(int* __restrict__ bsum, int nb,
                                      int* __restrict__ rowptr, int n) {
    __shared__ int s[256];
    int t = threadIdx.x;
    int v = (t < nb) ? bsum[t] : 0;
    s[t] = v;
    __syncthreads();
    for (int off = 1; off < 256; off <<= 1) {
        int x = (t >= off) ? s[t - off] : 0;
        __syncthreads();
        s[t] += x;
        __syncthreads();
    }
    if (t < nb) bsum[t] = s[t] - v;   // exclusive
    if (t == 255) rowptr[n] = s[255];
}

__global__ void scan_local_kernel(const int* __restrict__ deg, const int* __restrict__ bsum,
                                  int* __restrict__ rowptr, int* __restrict__ pos, int n) {
    __shared__ int s[256];
    int t = threadIdx.x;
    int base = blockIdx.x * 1024;
    int d[4];
    int sum = 0;
#pragma unroll
    for (int j = 0; j < 4; j++) {
        int i = base + t * 4 + j;
        d[j] = (i < n) ? deg[i] + 1 : 0;   // +1 self-loop
        sum += d[j];
    }
    s[t] = sum;
    __syncthreads();
    for (int off = 1; off < 256; off <<= 1) {
        int x = (t >= off) ? s[t - off] : 0;
        __syncthreads();
        s[t] += x;
        __syncthreads();
    }
    int run = bsum[blockIdx.x] + s[t] - sum;
#pragma unroll
    for (int j = 0; j < 4; j++) {
        int i = base + t * 4 + j;
        if (i < n) { rowptr[i] = run; pos[i] = run; }
        run += d[j];
    }
}

// merged fill: edges then self-loops; also records dst per slot
__global__ void fill_kernel(const int* __restrict__ src, const int* __restrict__ dst,
                            int* __restrict__ pos, int* __restrict__ col,
                            int* __restrict__ edst, int E, int N) {
    int i = blockIdx.x * blockDim.x + threadIdx.x;
    if (i < E) {
        int d = dst[i];
        int p = atomicAdd(&pos[d], 1);
        col[p] = src[i];
        edst[p] = d;
    } else if (i < E + N) {
        int n = i - E;
        int p = atomicAdd(&pos[n], 1);
        col[p] = n;
        edst[p] = n;
    }
}

// ---------------- tiled f32 GEMM (BM=64, BK=16, 256 threads) ----------------
template<int K, int NCOL, int TN, int MODE>
__global__ __launch_bounds__(256)
void tiled_gemm_kernel(const float* __restrict__ X, const float* __restrict__ W,
                       const float* __restrict__ v1, const float* __restrict__ v2,
                       const float* __restrict__ v3,
                       float* __restrict__ H, float* __restrict__ AS, float* __restrict__ AD,
                       int n_nodes) {
    const int t = threadIdx.x;
    const int tx = t & 15, ty = t >> 4;
    const int c0 = tx * TN;
    const int m0 = ty * 4;
    const int node0 = blockIdx.x * 64;

    __shared__ float As[16][68];
    __shared__ float Bs[16][NCOL];

    float acc[4][TN];
#pragma unroll
    for (int i = 0; i < 4; i++)
#pragma unroll
        for (int j = 0; j < TN; j++) acc[i][j] = 0.f;

    const int am = t >> 2, akq = t & 3;

    for (int kb = 0; kb < K; kb += 16) {
        float4 av = make_float4(0.f, 0.f, 0.f, 0.f);
        int anode = node0 + am;
        if (anode < n_nodes)
            av = *reinterpret_cast<const float4*>(X + (size_t)anode * K + kb + akq * 4);
        As[akq * 4 + 0][am] = av.x;
        As[akq * 4 + 1][am] = av.y;
        As[akq * 4 + 2][am] = av.z;
        As[akq * 4 + 3][am] = av.w;
        {
            const float4* wsrc = reinterpret_cast<const float4*>(W + (size_t)kb * NCOL);
            float4* bdst = reinterpret_cast<float4*>(&Bs[0][0]);
            for (int i = t; i < 16 * NCOL / 4; i += 256) bdst[i] = wsrc[i];
        }
        __syncthreads();
#pragma unroll
        for (int k = 0; k < 16; k++) {
            float4 a4 = *reinterpret_cast<const float4*>(&As[k][m0]);
            float a[4] = {a4.x, a4.y, a4.z, a4.w};
            float b[TN];
            if constexpr ((TN & 1) == 0) {
#pragma unroll
                for (int j = 0; j < TN / 2; j++) {
                    float2 b2 = *reinterpret_cast<const float2*>(&Bs[k][c0 + 2 * j]);
                    b[2 * j] = b2.x; b[2 * j + 1] = b2.y;
                }
            } else {
#pragma unroll
                for (int j = 0; j < TN; j++) b[j] = Bs[k][c0 + j];
            }
#pragma unroll
            for (int i = 0; i < 4; i++)
#pragma unroll
                for (int j = 0; j < TN; j++)
                    acc[i][j] = fmaf(a[i], b[j], acc[i][j]);
        }
        __syncthreads();
    }

    if constexpr (MODE == 0) {
        __shared__ float s_as[64][16];
        __shared__ float s_ad[64][16];
#pragma unroll
        for (int i = 0; i < 4; i++) {
            int node = node0 + m0 + i;
            float asp = 0.f, adp = 0.f;
#pragma unroll
            for (int j = 0; j < TN; j++) {
                asp = fmaf(acc[i][j], v1[c0 + j], asp);
                adp = fmaf(acc[i][j], v2[c0 + j], adp);
            }
            s_as[m0 + i][tx] = asp;
            s_ad[m0 + i][tx] = adp;
            if (node < n_nodes) {
#pragma unroll
                for (int j = 0; j < TN / 2; j++) {
                    float2 o;
                    o.x = acc[i][2 * j]; o.y = acc[i][2 * j + 1];
                    *reinterpret_cast<float2*>(H + (size_t)node * NCOL + c0 + 2 * j) = o;
                }
            }
        }
        __syncthreads();
        int m = t >> 2, head = t & 3;
        int node = node0 + m;
        if (node < n_nodes) {
            float s1 = s_as[m][head * 4 + 0] + s_as[m][head * 4 + 1]
                     + s_as[m][head * 4 + 2] + s_as[m][head * 4 + 3];
            float s2 = s_ad[m][head * 4 + 0] + s_ad[m][head * 4 + 1]
                     + s_ad[m][head * 4 + 2] + s_ad[m][head * 4 + 3];
            AS[(size_t)node * 4 + head] = s1;
            AD[(size_t)node * 4 + head] = s2;
        }
    } else {
        __shared__ float s_g[64][16];
#pragma unroll
        for (int i = 0; i < 4; i++) {
            float p = 0.f;
#pragma unroll
            for (int j = 0; j < TN; j++) {
                float a = acc[i][j] + v1[c0 + j];
                a = fmaxf(a, 0.f);
                p = fmaf(a, v2[c0 + j], p);
            }
            s_g[m0 + i][tx] = p;
        }
        __syncthreads();
        if (t < 64) {
            int node = node0 + t;
            if (node < n_nodes) {
                float s = 0.f;
#pragma unroll
                for (int j = 0; j < 16; j++) s += s_g[t][j];
                H[node] = s + v3[0];
            }
        }
    }
}

// ---------------- GAT pass 1: per-edge raw scores ----------------
__global__ void edge_score_kernel(const float4* __restrict__ AS4, const float4* __restrict__ AD4,
                                  const int* __restrict__ col, const int* __restrict__ edst,
                                  float4* __restrict__ ew4, int Etot) {
    int e = blockIdx.x * blockDim.x + threadIdx.x;
    if (e >= Etot) return;
    float4 a = AS4[col[e]];
    float4 b = AD4[edst[e]];
    float4 v;
    v.x = a.x + b.x; v.y = a.y + b.y; v.z = a.z + b.z; v.w = a.w + b.w;
    v.x = v.x > 0.f ? v.x : 0.2f * v.x;
    v.y = v.y > 0.f ? v.y : 0.2f * v.y;
    v.z = v.z > 0.f ? v.z : 0.2f * v.z;
    v.w = v.w > 0.f ? v.w : 0.2f * v.w;
    ew4[e] = v;
}

// ---------------- GAT pass 2: per-(node,head) softmax over in-edges ----------------
// in-place: ew <- exp(ew - max); invden[n*4+h] = 1/(sum+1e-16)
__global__ void edge_softmax_kernel(float* __restrict__ ew, const int* __restrict__ rowptr,
                                    float* __restrict__ invden, int n_nodes) {
    int tid = blockIdx.x * blockDim.x + threadIdx.x;
    int node = tid >> 2, h = tid & 3;
    if (node >= n_nodes) return;
    int beg = rowptr[node], end = rowptr[node + 1];
    float mx = -INFINITY;
    for (int e = beg; e < end; ++e) mx = fmaxf(mx, ew[(size_t)e * 4 + h]);
    float sum = 0.f;
    for (int e = beg; e < end; ++e) {
        float x = __expf(ew[(size_t)e * 4 + h] - mx);
        ew[(size_t)e * 4 + h] = x;
        sum += x;
    }
    invden[(size_t)node * 4 + h] = 1.f / (sum + 1e-16f);
}

// ---------------- GAT pass 3: gather-accumulate (wave per node, no shuffles) ----------------
__global__ __launch_bounds__(256)
void gat_gather_kernel(const float* __restrict__ H, const float* __restrict__ ew,
                       const float* __restrict__ invden, const int* __restrict__ rowptr,
                       const int* __restrict__ col, const float* __restrict__ bias,
                       float* __restrict__ OUT, int n_nodes) {
    int wid = threadIdx.x >> 6, lane = threadIdx.x & 63;
    int n = blockIdx.x * 4 + wid;
    if (n >= n_nodes) return;   // wave-uniform exit
    int beg = rowptr[n], end = rowptr[n + 1];
    int c = lane;
    bool cown = c < 48;
    int head_c = cown ? (c / 12) : 0;   // head of channels (2c,2c+1)
    const float2* __restrict__ Hc = reinterpret_cast<const float2*>(H) + c;

    float2 acc[8];
#pragma unroll
    for (int j = 0; j < 8; j++) acc[j] = make_float2(0.f, 0.f);

    for (int base = beg; base < end; base += 8) {
        int m = end - base;   // wave-uniform
        int s[8];
        float w[8];
#pragma unroll
        for (int j = 0; j < 8; j++) {
            if (j < m) {
                s[j] = col[base + j];                       // uniform addr -> broadcast
                w[j] = ew[(size_t)(base + j) * 4 + head_c]; // 4 addrs/edge, L2-hot
            }
        }
        if (cown) {
#pragma unroll
            for (int j = 0; j < 8; j++) {
                if (j < m) {
                    float2 v = Hc[(size_t)s[j] * 48];       // 8 independent gathers in flight
                    acc[j].x = fmaf(v.x, w[j], acc[j].x);
                    acc[j].y = fmaf(v.y, w[j], acc[j].y);
                }
            }
        }
    }

    if (cown) {
        float2 a;
        a.x = ((acc[0].x + acc[1].x) + (acc[2].x + acc[3].x))
            + ((acc[4].x + acc[5].x) + (acc[6].x + acc[7].x));
        a.y = ((acc[0].y + acc[1].y) + (acc[2].y + acc[3].y))
            + ((acc[4].y + acc[5].y) + (acc[6].y + acc[7].y));
        float inv = invden[(size_t)n * 4 + head_c];
        float2 b2 = reinterpret_cast<const float2*>(bias)[c];
        float ox = a.x * inv + b2.x;
        float oy = a.y * inv + b2.y;
        ox = ox > 0.f ? ox : (__expf(ox) - 1.f);   // ELU
        oy = oy > 0.f ? oy : (__expf(oy) - 1.f);
        reinterpret_cast<float2*>(OUT)[(size_t)n * 48 + c] = make_float2(ox, oy);
    }
}

// ---------------- pooling, stage 1: per-graph softmax stats (+pooled zeroing) ----------------
__device__ __forceinline__ int lower_bound_dev(const int* __restrict__ arr, int n, int key) {
    int lo = 0, hi = n;
    while (lo < hi) {
        int mid = (lo + hi) >> 1;
        if (arr[mid] < key) lo = mid + 1; else hi = mid;
    }
    return lo;
}

__global__ void gate_stats_kernel(const float* __restrict__ gate, const int* __restrict__ batch,
                                  int n_nodes, float* __restrict__ gm_out,
                                  float* __restrict__ inv_gden_out, float* __restrict__ pooled) {
    int g = blockIdx.x, t = threadIdx.x;   // 256 threads
    if (t < 96) pooled[(size_t)g * 96 + t] = 0.f;
    __shared__ int sb, se;
    __shared__ float sred[256];
    if (t == 0) {
        sb = lower_bound_dev(batch, n_nodes, g);
        se = lower_bound_dev(batch, n_nodes, g + 1);
    }
    __syncthreads();
    int beg = sb, end = se;

    float mx = -INFINITY;
    for (int i = beg + t; i < end; i += 256) mx = fmaxf(mx, gate[i]);
    sred[t] = mx;
    __syncthreads();
    for (int off = 128; off; off >>= 1) {
        if (t < off) sred[t] = fmaxf(sred[t], sred[t + off]);
        __syncthreads();
    }
    float gm = sred[0];
    if (!isfinite(gm)) gm = 0.f;
    __syncthreads();

    float sm = 0.f;
    for (int i = beg + t; i < end; i += 256) sm += __expf(gate[i] - gm);
    sred[t] = sm;
    __syncthreads();
    for (int off = 128; off; off >>= 1) {
        if (t < off) sred[t] += sred[t + off];
        __syncthreads();
    }
    if (t == 0) {
        gm_out[g] = gm;
        inv_gden_out[g] = 1.f / (sred[0] + 1e-16f);
    }
}

// ---------------- pooling, stage 2: weighted segment-sum over nodes ----------------
__global__ __launch_bounds__(384)
void pool_accum_kernel(const float* __restrict__ H2, const float* __restrict__ gate,
                       const int* __restrict__ batch, const float* __restrict__ gm,
                       const float* __restrict__ inv_gden, int n_nodes,
                       float* __restrict__ pooled) {
    const int NPB = 256;
    int t = threadIdx.x;
    int group = t / 96;
    int c = t - group * 96;
    if (group >= 4) return;
    int nbeg = blockIdx.x * NPB;
    int nend = min(nbeg + NPB, n_nodes);

    float acc = 0.f;
    int curg = -1;
    for (int i = nbeg + group; i < nend; i += 4) {
        int g = batch[i];
        if (g != curg) {
            if (curg >= 0) atomicAdd(&pooled[(size_t)curg * 96 + c], acc);
            acc = 0.f;
            curg = g;
        }
        float w = __expf(gate[i] - gm[curg]) * inv_gden[curg];
        acc = fmaf(w, H2[(size_t)i * 96 + c], acc);
    }
    if (curg >= 0) atomicAdd(&pooled[(size_t)curg * 96 + c], acc);
}

// ---------------- final MLP (one block per graph) ----------------
__global__ void final_kernel(const float* __restrict__ pooled, const float* __restrict__ f_w1,
                             const float* __restrict__ f_b1, const float* __restrict__ f_w2,
                             const float* __restrict__ f_b2, float* __restrict__ out) {
    int g = blockIdx.x, t = threadIdx.x;   // 96 threads
    __shared__ float sp[96], sh[96];
    sp[t] = pooled[(size_t)g * 96 + t];
    __syncthreads();
    float a = f_b1[t];
    for (int k = 0; k < 96; k++) a = fmaf(sp[k], f_w1[k * 96 + t], a);
    sh[t] = fmaxf(a, 0.f);
    __syncthreads();
    if (t < 3) {
        float o = f_b2[t];
        for (int k = 0; k < 96; k++) o = fmaf(sh[k], f_w2[k * 3 + t], o);
        out[g * 3 + t] = o;
    }
}

// ---------------- launch ----------------
extern "C" void kernel_launch(void* const* d_in, const int* in_sizes, int n_in,
                              void* d_out, int out_size, void* d_ws, size_t ws_size,
                              hipStream_t stream) {
    const float* x    = (const float*)d_in[0];
    const int*   ei   = (const int*)d_in[1];
    const int*   batch= (const int*)d_in[2];
    const float* W1   = (const float*)d_in[4];
    const float* as1  = (const float*)d_in[5];
    const float* ad1  = (const float*)d_in[6];
    const float* b1   = (const float*)d_in[7];
    const float* W2   = (const float*)d_in[8];
    const float* as2  = (const float*)d_in[9];
    const float* ad2  = (const float*)d_in[10];
    const float* b2   = (const float*)d_in[11];
    const float* g_w1 = (const float*)d_in[12];
    const float* g_b1 = (const float*)d_in[13];
    const float* g_w2 = (const float*)d_in[14];
    const float* g_b2 = (const float*)d_in[15];
    const float* f_w1 = (const float*)d_in[16];
    const float* f_b1 = (const float*)d_in[17];
    const float* f_w2 = (const float*)d_in[18];
    const float* f_b2 = (const float*)d_in[19];
    float* out = (float*)d_out;

    int N = in_sizes[0] / 128;
    int E = in_sizes[1] / 2;
    int G = out_size / 3;
    int Etot = E + N;
    const int* srcv = ei;
    const int* dstv = ei + E;

    char* p = (char*)d_ws;
    auto alloc = [&](size_t bytes) {
        char* q = p;
        p += (bytes + 255) & ~(size_t)255;
        return q;
    };
    float* hA    = (float*)alloc((size_t)N * 96 * 4);
    float* hB    = (float*)alloc((size_t)N * 96 * 4);
    float* AS    = (float*)alloc((size_t)N * 4 * 4);
    float* AD    = (float*)alloc((size_t)N * 4 * 4);
    float* invden= (float*)alloc((size_t)N * 4 * 4);
    float* gatev = (float*)alloc((size_t)N * 4);
    float* pooled= (float*)alloc((size_t)G * 96 * 4);
    float* gmv   = (float*)alloc((size_t)G * 4);
    float* invgd = (float*)alloc((size_t)G * 4);
    int*   deg   = (int*)alloc((size_t)N * 4);
    int*   pos   = (int*)alloc((size_t)N * 4);
    int*   rowptr= (int*)alloc(((size_t)N + 1) * 4);
    int*   bsum  = (int*)alloc((size_t)256 * 4);
    int*   col   = (int*)alloc((size_t)Etot * 4);
    int*   edst  = (int*)alloc((size_t)Etot * 4);
    float* ew    = (float*)alloc((size_t)Etot * 4 * 4);

    const int B = 256;
    int gemm_blocks = (N + 63) / 64;
    int nb_scan = (N + 1023) / 1024;

    // CSR build (by dst, self-loops folded into scan as +1)
    hipMemsetAsync(deg, 0, (size_t)N * 4, stream);
    hist_kernel<<<(E + B - 1) / B, B, 0, stream>>>(dstv, deg, E);
    scan_bsum_kernel<<<nb_scan, 256, 0, stream>>>(deg, bsum, N);
    scan_bsum_scan_kernel<<<1, 256, 0, stream>>>(bsum, nb_scan, rowptr, N);
    scan_local_kernel<<<nb_scan, 256, 0, stream>>>(deg, bsum, rowptr, pos, N);
    fill_kernel<<<(Etot + B - 1) / B, B, 0, stream>>>(srcv, dstv, pos, col, edst, E, N);

    // layer 1
    tiled_gemm_kernel<128, 96, 6, 0><<<gemm_blocks, 256, 0, stream>>>(
        x, W1, as1, ad1, nullptr, hA, AS, AD, N);
    edge_score_kernel<<<(Etot + B - 1) / B, B, 0, stream>>>(
        (const float4*)AS, (const float4*)AD, col, edst, (float4*)ew, Etot);
    edge_softmax_kernel<<<(4 * N + B - 1) / B, B, 0, stream>>>(ew, rowptr, invden, N);
    gat_gather_kernel<<<(N + 3) / 4, 256, 0, stream>>>(hA, ew, invden, rowptr, col, b1, hB, N);
    // layer 2
    tiled_gemm_kernel<96, 96, 6, 0><<<gemm_blocks, 256, 0, stream>>>(
        hB, W2, as2, ad2, nullptr, hA, AS, AD, N);
    edge_score_kernel<<<(Etot + B - 1) / B, B, 0, stream>>>(
        (const float4*)AS, (const float4*)AD, col, edst, (float4*)ew, Etot);
    edge_softmax_kernel<<<(4 * N + B - 1) / B, B, 0, stream>>>(ew, rowptr, invden, N);
    gat_gather_kernel<<<(N + 3) / 4, 256, 0, stream>>>(hA, ew, invden, rowptr, col, b2, hB, N);

    // pooling
    tiled_gemm_kernel<96, 48, 3, 1><<<gemm_blocks, 256, 0, stream>>>(
        hB, g_w1, g_b1, g_w2, g_b2, gatev, nullptr, nullptr, N);
    gate_stats_kernel<<<G, 256, 0, stream>>>(gatev, batch, N, gmv, invgd, pooled);
    pool_accum_kernel<<<(N + 255) / 256, 384, 0, stream>>>(
        hB, gatev, batch, gmv, invgd, N, pooled);
    final_kernel<<<G, 96, 0, stream>>>(pooled, f_w1, f_b1, f_w2, f_b2, out);
}